// Round 9
// baseline (141.874 us; speedup 1.0000x reference)
//
#include <hip/hip_runtime.h>

// ---------------------------------------------------------------------------
// SGConv (K=2): out = A^2 (X W^T) + b,  A = D^{-1/2}(Adj_clamped + I)D^{-1/2}
// N=50000, E=800000, T=256, H=128. edge_index arrives as int32.
//
// r9: transform x-tile staged through LDS with coalesced float4 loads
// (fixes the 1KB-strided fragment loads that made r8 latency-bound).
// CSR build: two-pass bucket sort (r8, unchanged). Hops: unroll-8 (r7).
// ---------------------------------------------------------------------------

typedef __attribute__((ext_vector_type(8))) short short8_t;   // 8 bf16
typedef __attribute__((ext_vector_type(4))) float f32x4_t;    // MFMA acc

constexpr int BK    = 256;   // nodes per bucket
constexpr int CAP   = 8192;  // records per bucket (mean 4096 + 64 sigma)
constexpr int CHUNK = 4096;  // edges per passA block

__device__ inline unsigned short f2bf(float f) {               // RNE f32->bf16
    unsigned int u = __float_as_uint(f);
    return (unsigned short)((u + 0x7fffu + ((u >> 16) & 1u)) >> 16);
}
__device__ inline float bf_lo(unsigned int u) { return __uint_as_float(u << 16); }
__device__ inline float bf_hi(unsigned int u) { return __uint_as_float(u & 0xffff0000u); }

// ---- passA: bucket-bin edges; coalesced appends to bucket storage ----
__global__ __launch_bounds__(256) void k_passA(
    const int* __restrict__ rows, const int* __restrict__ cols,
    const float* __restrict__ ew, int E,
    unsigned int* __restrict__ bwr,   // [NB*CAP]  w<<16|row
    unsigned char* __restrict__ bcl,  // [NB*CAP]  col low byte
    int* __restrict__ tails,          // [NB]
    const float* __restrict__ W, unsigned short* __restrict__ Wbf, int WT)
{
    const int tid = threadIdx.x;
    const int gid = blockIdx.x * 256 + tid;
    if (gid < WT) Wbf[gid] = f2bf(W[gid]);       // fold W->bf16 conversion

    __shared__ unsigned short lcol[CHUNK], lrow[CHUNK], lw[CHUNK];
    __shared__ unsigned short sidx[CHUNK];
    __shared__ int hist[256], lofs[256], fill[256], gbase[256];

    const int e0  = blockIdx.x * CHUNK;
    const int cnt = min(CHUNK, E - e0);
    if (cnt <= 0) return;

    hist[tid] = 0; fill[tid] = 0;
    __syncthreads();

    for (int i = tid; i < cnt; i += 256) {
        const int c = cols[e0 + i];
        const int r = rows[e0 + i];
        float w = ew[e0 + i];
        w = (w > 0.0f) ? w : 1e-7f;              // elu(w)<=0 <=> w<=0
        lcol[i] = (unsigned short)c;
        lrow[i] = (unsigned short)r;
        lw[i]   = f2bf(w);
        atomicAdd(&hist[c >> 8], 1);
    }
    __syncthreads();

    // exclusive scan of hist -> lofs
    {
        const int v = hist[tid];
        lofs[tid] = v;
        __syncthreads();
        for (int off = 1; off < 256; off <<= 1) {
            int t = (tid >= off) ? lofs[tid - off] : 0;
            __syncthreads();
            lofs[tid] += t;
            __syncthreads();
        }
        const int excl = lofs[tid] - v;
        __syncthreads();
        lofs[tid] = excl;
        __syncthreads();
    }

    // rank within block -> sorted index
    for (int i = tid; i < cnt; i += 256) {
        const int b = lcol[i] >> 8;
        const int pos = lofs[b] + atomicAdd(&fill[b], 1);
        sidx[pos] = (unsigned short)i;
    }
    __syncthreads();

    // reserve global space: one atomic per non-empty bucket
    {
        const int h = hist[tid];
        gbase[tid] = (h > 0) ? atomicAdd(&tails[tid], h) : 0;
    }
    __syncthreads();

    // write out in bucket-sorted order (runs of consecutive addresses)
    for (int i = tid; i < cnt; i += 256) {
        const int e = sidx[i];
        const int b = lcol[e] >> 8;
        const int slot = gbase[b] + (i - lofs[b]);
        if (slot < CAP) {                         // overflow guard
            const int addr = b * CAP + slot;
            bwr[addr] = ((unsigned int)lw[e] << 16) | lrow[e];
            bcl[addr] = (unsigned char)(lcol[e] & 255);
        }
    }
}

// ---- passB: per-bucket LDS sort + dis/starts/ends; coalesced meta write ----
__global__ __launch_bounds__(256) void k_passB(
    const unsigned int* __restrict__ bwr, const unsigned char* __restrict__ bcl,
    const int* __restrict__ tails,
    unsigned int* __restrict__ meta, int* __restrict__ starts,
    int* __restrict__ ends, float* __restrict__ dis, int N)
{
    const int tid  = threadIdx.x;
    const int b    = blockIdx.x;
    const int base = b * CAP;
    const int cnt  = min(tails[b], CAP);

    __shared__ unsigned int  lwr[CAP];      // 32 KB
    __shared__ unsigned char lcl[CAP];      // 8 KB
    __shared__ unsigned int  srt[CAP];      // 32 KB
    __shared__ int hist[256], offs[256], fill[256];

    hist[tid] = 0; fill[tid] = 0;
    __syncthreads();

    for (int i = tid; i < cnt; i += 256) {
        lwr[i] = bwr[base + i];
        unsigned char c = bcl[base + i];
        lcl[i] = c;
        atomicAdd(&hist[c], 1);
    }
    __syncthreads();

    // exclusive scan of hist -> offs
    {
        const int v = hist[tid];
        offs[tid] = v;
        __syncthreads();
        for (int off = 1; off < 256; off <<= 1) {
            int t = (tid >= off) ? offs[tid - off] : 0;
            __syncthreads();
            offs[tid] += t;
            __syncthreads();
        }
        const int excl = offs[tid] - v;
        __syncthreads();
        offs[tid] = excl;
        __syncthreads();
    }

    // scatter to sorted order (LDS -> LDS)
    for (int i = tid; i < cnt; i += 256) {
        const int c = lcl[i];
        const int pos = offs[c] + atomicAdd(&fill[c], 1);
        srt[pos] = lwr[i];
    }
    __syncthreads();

    // coalesced meta write
    for (int i = tid; i < cnt; i += 256) meta[base + i] = srt[i];

    // per-node: dis = rsqrt(1 + sum w), starts/ends
    const int node = b * BK + tid;
    if (node < N) {
        const int s = offs[tid];
        const int t = s + hist[tid];
        float sum = 1.0f;                         // self-loop
        for (int j = s; j < t; ++j) sum += bf_hi(srt[j]);
        dis[node]    = rsqrtf(sum);
        starts[node] = base + s;
        ends[node]   = base + t;
    }
}

// ---- z[r][h] = bf16( dis[r] * dot(x[r], W[h]) ) via MFMA bf16 ----
// r9: 64-row x tile staged to LDS (bf16) with coalesced float4 loads.
__global__ __launch_bounds__(256) void k_transform_mfma(
    const float* __restrict__ x, const unsigned short* __restrict__ Wbf,
    const float* __restrict__ dis, unsigned short* __restrict__ z, int N)
{
    constexpr int RB  = 64;
    constexpr int LDK = 264;   // 256 + 8 pad; row stride 528 B (16B-aligned, 4-bank shift/row)
    __shared__ unsigned short xs[RB][LDK];

    const int tid = threadIdx.x;
    const int r0  = blockIdx.x * RB;

    // stage: 64 rows x 64 float4 chunks, coalesced; convert to bf16
    {
        const float4* x4 = reinterpret_cast<const float4*>(x);
        for (int i = tid; i < RB * 64; i += 256) {
            const int rr  = i >> 6;
            const int c4  = i & 63;
            const int row = r0 + rr;
            float4 v = make_float4(0.f, 0.f, 0.f, 0.f);
            if (row < N) v = x4[(size_t)row * 64 + c4];
            unsigned short* p = &xs[rr][c4 * 4];
            p[0] = f2bf(v.x); p[1] = f2bf(v.y);
            p[2] = f2bf(v.z); p[3] = f2bf(v.w);
        }
    }
    __syncthreads();

    const int wave = tid >> 6;
    const int lane = tid & 63;
    const int lr   = lane & 15;     // A-row / D-col within tile
    const int kg   = lane >> 4;     // k-group (8 consecutive k each)
    const int wr0  = wave * 16;     // this wave's row offset in the block

    f32x4_t acc[8];
#pragma unroll
    for (int n = 0; n < 8; ++n) acc[n] = (f32x4_t){0.f, 0.f, 0.f, 0.f};

    for (int k0 = 0; k0 < 256; k0 += 32) {
        const int kb = k0 + kg * 8;
        short8_t af = *reinterpret_cast<const short8_t*>(&xs[wr0 + lr][kb]);
#pragma unroll
        for (int n = 0; n < 8; ++n) {
            short8_t bf = *reinterpret_cast<const short8_t*>(
                Wbf + (size_t)(n * 16 + lr) * 256 + kb);
            acc[n] = __builtin_amdgcn_mfma_f32_16x16x32_bf16(af, bf, acc[n], 0, 0, 0);
        }
    }

    // D layout: col = lane&15, row = (lane>>4)*4 + reg   [m89/m91]
    float dsc[4];
#pragma unroll
    for (int r = 0; r < 4; ++r) {
        const int orow = r0 + wr0 + kg * 4 + r;
        dsc[r] = (orow < N) ? dis[orow] : 0.f;
    }
#pragma unroll
    for (int n = 0; n < 8; ++n) {
#pragma unroll
        for (int r = 0; r < 4; ++r) {
            const int orow = r0 + wr0 + kg * 4 + r;
            if (orow < N)
                z[(size_t)orow * 128 + n * 16 + lr] = f2bf(dsc[r] * acc[n][r]);
        }
    }
}

// ---- hop: one wave per dst node, unroll-8 independent gathers ----
// acc = z[c] + sum w*z[r];  FINAL: out=dis*acc+bias (f32); else bf16(dis^2*acc)
template <bool FINAL>
__global__ __launch_bounds__(256) void k_hop(
    const int* __restrict__ starts, const int* __restrict__ ends,
    const unsigned int* __restrict__ meta,
    const float* __restrict__ dis, const unsigned int* __restrict__ hin,
    const float* __restrict__ bias, void* __restrict__ hout, int N)
{
    const int wave = threadIdx.x >> 6;
    const int lane = threadIdx.x & 63;
    const int node = blockIdx.x * 4 + wave;
    if (node >= N) return;

    const int s = __builtin_amdgcn_readfirstlane(starts[node]);
    const int t = __builtin_amdgcn_readfirstlane(ends[node]);
    const float d = dis[node];

    unsigned int v = hin[(size_t)node * 64 + lane];
    float ax = bf_lo(v), ay = bf_hi(v);            // self term z[c]

    int j = s;
    for (; j + 8 <= t; j += 8) {
        unsigned int m0 = meta[j],     m1 = meta[j + 1];
        unsigned int m2 = meta[j + 2], m3 = meta[j + 3];
        unsigned int m4 = meta[j + 4], m5 = meta[j + 5];
        unsigned int m6 = meta[j + 6], m7 = meta[j + 7];
        unsigned int u0 = hin[(size_t)(m0 & 0xffffu) * 64 + lane];
        unsigned int u1 = hin[(size_t)(m1 & 0xffffu) * 64 + lane];
        unsigned int u2 = hin[(size_t)(m2 & 0xffffu) * 64 + lane];
        unsigned int u3 = hin[(size_t)(m3 & 0xffffu) * 64 + lane];
        unsigned int u4 = hin[(size_t)(m4 & 0xffffu) * 64 + lane];
        unsigned int u5 = hin[(size_t)(m5 & 0xffffu) * 64 + lane];
        unsigned int u6 = hin[(size_t)(m6 & 0xffffu) * 64 + lane];
        unsigned int u7 = hin[(size_t)(m7 & 0xffffu) * 64 + lane];
        ax += bf_hi(m0) * bf_lo(u0); ay += bf_hi(m0) * bf_hi(u0);
        ax += bf_hi(m1) * bf_lo(u1); ay += bf_hi(m1) * bf_hi(u1);
        ax += bf_hi(m2) * bf_lo(u2); ay += bf_hi(m2) * bf_hi(u2);
        ax += bf_hi(m3) * bf_lo(u3); ay += bf_hi(m3) * bf_hi(u3);
        ax += bf_hi(m4) * bf_lo(u4); ay += bf_hi(m4) * bf_hi(u4);
        ax += bf_hi(m5) * bf_lo(u5); ay += bf_hi(m5) * bf_hi(u5);
        ax += bf_hi(m6) * bf_lo(u6); ay += bf_hi(m6) * bf_hi(u6);
        ax += bf_hi(m7) * bf_lo(u7); ay += bf_hi(m7) * bf_hi(u7);
    }
    for (; j < t; ++j) {
        unsigned int m = meta[j];
        const float w = bf_hi(m);
        unsigned int u = hin[(size_t)(m & 0xffffu) * 64 + lane];
        ax += w * bf_lo(u); ay += w * bf_hi(u);
    }

    if (FINAL) {
        float2 bv = reinterpret_cast<const float2*>(bias)[lane];
        float2 o; o.x = d * ax + bv.x; o.y = d * ay + bv.y;
        reinterpret_cast<float2*>(hout)[(size_t)node * 64 + lane] = o;
    } else {
        const float d2 = d * d;
        unsigned int p = (unsigned int)f2bf(d2 * ax) |
                         ((unsigned int)f2bf(d2 * ay) << 16);
        reinterpret_cast<unsigned int*>(hout)[(size_t)node * 64 + lane] = p;
    }
}

extern "C" void kernel_launch(void* const* d_in, const int* in_sizes, int n_in,
                              void* d_out, int out_size, void* d_ws, size_t ws_size,
                              hipStream_t stream)
{
    const float* x  = (const float*)d_in[0];
    const int*   ei = (const int*)d_in[1];     // int32 (harness converts)
    const float* ew = (const float*)d_in[2];
    const float* W  = (const float*)d_in[3];
    const float* b  = (const float*)d_in[4];

    const int E  = in_sizes[2];
    const int H  = in_sizes[4];        // 128
    const int T  = in_sizes[3] / H;    // 256
    const int N  = in_sizes[0] / T;    // 50000  (< 65536: 16-bit ids valid)
    const int WT = in_sizes[3];        // 32768
    const int NB = (N + BK - 1) / BK;  // 196 buckets

    const int* rows = ei;              // sources
    const int* cols = ei + E;          // targets (aggregation index)

    // ---- workspace ----
    char* wsb = (char*)d_ws;
    unsigned int*   z    = (unsigned int*)wsb;   wsb += (size_t)N * (H / 2) * 4;  // 12.8 MB
    unsigned int*   z1   = (unsigned int*)wsb;   wsb += (size_t)N * (H / 2) * 4;  // 12.8 MB
    unsigned int*   meta = (unsigned int*)wsb;   wsb += (size_t)NB * CAP * 4;     // 6.4 MB
    unsigned short* Wbf  = (unsigned short*)wsb; wsb += (size_t)WT * 2;           // 64 KB
    float*          dis  = (float*)wsb;          wsb += (size_t)N * 4;
    int*            sta  = (int*)wsb;            wsb += (size_t)N * 4;
    int*            end_ = (int*)wsb;            wsb += (size_t)N * 4;
    int*            tails= (int*)wsb;            wsb += (size_t)NB * 4;
    // bucket staging aliases z1 (dead until hop1 output): bwr 6.4MB + bcl 1.6MB
    unsigned int*   bwr  = z1;                                  // NB*CAP*4
    unsigned char*  bcl  = (unsigned char*)(z1 + (size_t)NB * CAP);

    float* out = (float*)d_out;

    // CSR build: bucket two-pass
    hipMemsetAsync(tails, 0, (size_t)NB * 4, stream);
    {
        const int nblkA = (E + CHUNK - 1) / CHUNK;   // 196 (covers WT too)
        k_passA<<<nblkA, 256, 0, stream>>>(rows, cols, ew, E,
                                           bwr, bcl, tails, W, Wbf, WT);
        k_passB<<<NB, 256, 0, stream>>>(bwr, bcl, tails,
                                        meta, sta, end_, dis, N);
    }

    // transform: z = bf16(dis * (X W^T))
    {
        const int RB = 64;
        k_transform_mfma<<<(N + RB - 1) / RB, 256, 0, stream>>>(
            x, Wbf, dis, (unsigned short*)z, N);
    }

    // hops (hop1 overwrites z1 -> bucket staging dead by then)
    const int gH = (N + 3) / 4;
    k_hop<false><<<gH, 256, 0, stream>>>(sta, end_, meta, dis, z, nullptr, z1, N);
    k_hop<true ><<<gH, 256, 0, stream>>>(sta, end_, meta, dis, z1, b, out, N);
}

// Round 10
// 139.806 us; speedup vs baseline: 1.0148x; 1.0148x over previous
//
#include <hip/hip_runtime.h>

// ---------------------------------------------------------------------------
// SGConv (K=2): out = A^2 (X W^T) + b,  A = D^{-1/2}(Adj_clamped + I)D^{-1/2}
// N=50000, E=800000, T=256, H=128. edge_index arrives as int32.
//
// r10: transform restructured — W fragments preloaded to VGPRs (wave = 16
// rows x 64 cols, 4 n-tiles x 8 k = 32 frags = 128 VGPR), x staged to LDS.
// k-loop is pure ds_read+MFMA (no global loads -> nothing to stall on).
// CSR build: two-pass bucket sort (r8). Hops: unroll-8 gather (r7).
// ---------------------------------------------------------------------------

typedef __attribute__((ext_vector_type(8))) short short8_t;   // 8 bf16
typedef __attribute__((ext_vector_type(4))) float f32x4_t;    // MFMA acc

constexpr int BK    = 256;   // nodes per bucket
constexpr int CAP   = 8192;  // records per bucket (mean 4096 + 64 sigma)
constexpr int CHUNK = 4096;  // edges per passA block

__device__ inline unsigned short f2bf(float f) {               // RNE f32->bf16
    unsigned int u = __float_as_uint(f);
    return (unsigned short)((u + 0x7fffu + ((u >> 16) & 1u)) >> 16);
}
__device__ inline float bf_lo(unsigned int u) { return __uint_as_float(u << 16); }
__device__ inline float bf_hi(unsigned int u) { return __uint_as_float(u & 0xffff0000u); }

// ---- passA: bucket-bin edges; coalesced appends to bucket storage ----
__global__ __launch_bounds__(256) void k_passA(
    const int* __restrict__ rows, const int* __restrict__ cols,
    const float* __restrict__ ew, int E,
    unsigned int* __restrict__ bwr,   // [NB*CAP]  w<<16|row
    unsigned char* __restrict__ bcl,  // [NB*CAP]  col low byte
    int* __restrict__ tails,          // [NB]
    const float* __restrict__ W, unsigned short* __restrict__ Wbf, int WT)
{
    const int tid = threadIdx.x;
    const int gid = blockIdx.x * 256 + tid;
    if (gid < WT) Wbf[gid] = f2bf(W[gid]);       // fold W->bf16 conversion

    __shared__ unsigned short lcol[CHUNK], lrow[CHUNK], lw[CHUNK];
    __shared__ unsigned short sidx[CHUNK];
    __shared__ int hist[256], lofs[256], fill[256], gbase[256];

    const int e0  = blockIdx.x * CHUNK;
    const int cnt = min(CHUNK, E - e0);
    if (cnt <= 0) return;

    hist[tid] = 0; fill[tid] = 0;
    __syncthreads();

    for (int i = tid; i < cnt; i += 256) {
        const int c = cols[e0 + i];
        const int r = rows[e0 + i];
        float w = ew[e0 + i];
        w = (w > 0.0f) ? w : 1e-7f;              // elu(w)<=0 <=> w<=0
        lcol[i] = (unsigned short)c;
        lrow[i] = (unsigned short)r;
        lw[i]   = f2bf(w);
        atomicAdd(&hist[c >> 8], 1);
    }
    __syncthreads();

    // exclusive scan of hist -> lofs
    {
        const int v = hist[tid];
        lofs[tid] = v;
        __syncthreads();
        for (int off = 1; off < 256; off <<= 1) {
            int t = (tid >= off) ? lofs[tid - off] : 0;
            __syncthreads();
            lofs[tid] += t;
            __syncthreads();
        }
        const int excl = lofs[tid] - v;
        __syncthreads();
        lofs[tid] = excl;
        __syncthreads();
    }

    // rank within block -> sorted index
    for (int i = tid; i < cnt; i += 256) {
        const int b = lcol[i] >> 8;
        const int pos = lofs[b] + atomicAdd(&fill[b], 1);
        sidx[pos] = (unsigned short)i;
    }
    __syncthreads();

    // reserve global space: one atomic per non-empty bucket
    {
        const int h = hist[tid];
        gbase[tid] = (h > 0) ? atomicAdd(&tails[tid], h) : 0;
    }
    __syncthreads();

    // write out in bucket-sorted order (runs of consecutive addresses)
    for (int i = tid; i < cnt; i += 256) {
        const int e = sidx[i];
        const int b = lcol[e] >> 8;
        const int slot = gbase[b] + (i - lofs[b]);
        if (slot < CAP) {                         // overflow guard
            const int addr = b * CAP + slot;
            bwr[addr] = ((unsigned int)lw[e] << 16) | lrow[e];
            bcl[addr] = (unsigned char)(lcol[e] & 255);
        }
    }
}

// ---- passB: per-bucket LDS sort + dis/starts/ends; coalesced meta write ----
__global__ __launch_bounds__(256) void k_passB(
    const unsigned int* __restrict__ bwr, const unsigned char* __restrict__ bcl,
    const int* __restrict__ tails,
    unsigned int* __restrict__ meta, int* __restrict__ starts,
    int* __restrict__ ends, float* __restrict__ dis, int N)
{
    const int tid  = threadIdx.x;
    const int b    = blockIdx.x;
    const int base = b * CAP;
    const int cnt  = min(tails[b], CAP);

    __shared__ unsigned int  lwr[CAP];      // 32 KB
    __shared__ unsigned char lcl[CAP];      // 8 KB
    __shared__ unsigned int  srt[CAP];      // 32 KB
    __shared__ int hist[256], offs[256], fill[256];

    hist[tid] = 0; fill[tid] = 0;
    __syncthreads();

    for (int i = tid; i < cnt; i += 256) {
        lwr[i] = bwr[base + i];
        unsigned char c = bcl[base + i];
        lcl[i] = c;
        atomicAdd(&hist[c], 1);
    }
    __syncthreads();

    // exclusive scan of hist -> offs
    {
        const int v = hist[tid];
        offs[tid] = v;
        __syncthreads();
        for (int off = 1; off < 256; off <<= 1) {
            int t = (tid >= off) ? offs[tid - off] : 0;
            __syncthreads();
            offs[tid] += t;
            __syncthreads();
        }
        const int excl = offs[tid] - v;
        __syncthreads();
        offs[tid] = excl;
        __syncthreads();
    }

    // scatter to sorted order (LDS -> LDS)
    for (int i = tid; i < cnt; i += 256) {
        const int c = lcl[i];
        const int pos = offs[c] + atomicAdd(&fill[c], 1);
        srt[pos] = lwr[i];
    }
    __syncthreads();

    // coalesced meta write
    for (int i = tid; i < cnt; i += 256) meta[base + i] = srt[i];

    // per-node: dis = rsqrt(1 + sum w), starts/ends
    const int node = b * BK + tid;
    if (node < N) {
        const int s = offs[tid];
        const int t = s + hist[tid];
        float sum = 1.0f;                         // self-loop
        for (int j = s; j < t; ++j) sum += bf_hi(srt[j]);
        dis[node]    = rsqrtf(sum);
        starts[node] = base + s;
        ends[node]   = base + t;
    }
}

// ---- z[r][h] = bf16( dis[r] * dot(x[r], W[h]) ) via MFMA bf16 ----
// r10: wave = 16 rows x 64 cols; W frags preloaded to VGPRs; x in LDS.
__global__ __launch_bounds__(256, 2) void k_transform_mfma(
    const float* __restrict__ x, const unsigned short* __restrict__ Wbf,
    const float* __restrict__ dis, unsigned short* __restrict__ z, int N)
{
    constexpr int RB  = 32;
    constexpr int LDK = 264;   // 256 + 8 pad shorts; row stride 528 B
    __shared__ unsigned short xs[RB][LDK];

    const int tid  = threadIdx.x;
    const int r0   = blockIdx.x * RB;
    const int wave = tid >> 6;
    const int lane = tid & 63;
    const int lr   = lane & 15;     // A-row / D-col within tile
    const int kg   = lane >> 4;     // k-group (8 consecutive k each)
    const int nb   = (wave & 1) * 4;    // n-tile base: cols nb*16 .. nb*16+63
    const int wr0  = (wave >> 1) * 16;  // row offset within block (0 or 16)

    // preload this wave's 32 W fragments (4 n-tiles x 8 k-steps) to VGPRs.
    // All independent 16B loads; L2-broadcast across blocks.
    short8_t wf[4][8];
#pragma unroll
    for (int n = 0; n < 4; ++n)
#pragma unroll
        for (int k = 0; k < 8; ++k)
            wf[n][k] = *reinterpret_cast<const short8_t*>(
                Wbf + (size_t)((nb + n) * 16 + lr) * 256 + k * 32 + kg * 8);

    // stage: 32 rows x 64 float4 chunks, coalesced; convert to bf16
    {
        const float4* x4 = reinterpret_cast<const float4*>(x);
        for (int i = tid; i < RB * 64; i += 256) {
            const int rr  = i >> 6;
            const int c4  = i & 63;
            const int row = r0 + rr;
            float4 v = make_float4(0.f, 0.f, 0.f, 0.f);
            if (row < N) v = x4[(size_t)row * 64 + c4];
            unsigned short* p = &xs[rr][c4 * 4];
            p[0] = f2bf(v.x); p[1] = f2bf(v.y);
            p[2] = f2bf(v.z); p[3] = f2bf(v.w);
        }
    }
    __syncthreads();

    f32x4_t acc[4];
#pragma unroll
    for (int n = 0; n < 4; ++n) acc[n] = (f32x4_t){0.f, 0.f, 0.f, 0.f};

#pragma unroll
    for (int k = 0; k < 8; ++k) {
        const short8_t af =
            *reinterpret_cast<const short8_t*>(&xs[wr0 + lr][k * 32 + kg * 8]);
#pragma unroll
        for (int n = 0; n < 4; ++n)
            acc[n] = __builtin_amdgcn_mfma_f32_16x16x32_bf16(af, wf[n][k],
                                                             acc[n], 0, 0, 0);
    }

    // D layout: col = lane&15, row = (lane>>4)*4 + reg   [m89/m91]
    float dsc[4];
#pragma unroll
    for (int r = 0; r < 4; ++r) {
        const int orow = r0 + wr0 + kg * 4 + r;
        dsc[r] = (orow < N) ? dis[orow] : 0.f;
    }
#pragma unroll
    for (int n = 0; n < 4; ++n) {
#pragma unroll
        for (int r = 0; r < 4; ++r) {
            const int orow = r0 + wr0 + kg * 4 + r;
            if (orow < N)
                z[(size_t)orow * 128 + (nb + n) * 16 + lr] =
                    f2bf(dsc[r] * acc[n][r]);
        }
    }
}

// ---- hop: one wave per dst node, unroll-8 independent gathers ----
// acc = z[c] + sum w*z[r];  FINAL: out=dis*acc+bias (f32); else bf16(dis^2*acc)
template <bool FINAL>
__global__ __launch_bounds__(256) void k_hop(
    const int* __restrict__ starts, const int* __restrict__ ends,
    const unsigned int* __restrict__ meta,
    const float* __restrict__ dis, const unsigned int* __restrict__ hin,
    const float* __restrict__ bias, void* __restrict__ hout, int N)
{
    const int wave = threadIdx.x >> 6;
    const int lane = threadIdx.x & 63;
    const int node = blockIdx.x * 4 + wave;
    if (node >= N) return;

    const int s = __builtin_amdgcn_readfirstlane(starts[node]);
    const int t = __builtin_amdgcn_readfirstlane(ends[node]);
    const float d = dis[node];

    unsigned int v = hin[(size_t)node * 64 + lane];
    float ax = bf_lo(v), ay = bf_hi(v);            // self term z[c]

    int j = s;
    for (; j + 8 <= t; j += 8) {
        unsigned int m0 = meta[j],     m1 = meta[j + 1];
        unsigned int m2 = meta[j + 2], m3 = meta[j + 3];
        unsigned int m4 = meta[j + 4], m5 = meta[j + 5];
        unsigned int m6 = meta[j + 6], m7 = meta[j + 7];
        unsigned int u0 = hin[(size_t)(m0 & 0xffffu) * 64 + lane];
        unsigned int u1 = hin[(size_t)(m1 & 0xffffu) * 64 + lane];
        unsigned int u2 = hin[(size_t)(m2 & 0xffffu) * 64 + lane];
        unsigned int u3 = hin[(size_t)(m3 & 0xffffu) * 64 + lane];
        unsigned int u4 = hin[(size_t)(m4 & 0xffffu) * 64 + lane];
        unsigned int u5 = hin[(size_t)(m5 & 0xffffu) * 64 + lane];
        unsigned int u6 = hin[(size_t)(m6 & 0xffffu) * 64 + lane];
        unsigned int u7 = hin[(size_t)(m7 & 0xffffu) * 64 + lane];
        ax += bf_hi(m0) * bf_lo(u0); ay += bf_hi(m0) * bf_hi(u0);
        ax += bf_hi(m1) * bf_lo(u1); ay += bf_hi(m1) * bf_hi(u1);
        ax += bf_hi(m2) * bf_lo(u2); ay += bf_hi(m2) * bf_hi(u2);
        ax += bf_hi(m3) * bf_lo(u3); ay += bf_hi(m3) * bf_hi(u3);
        ax += bf_hi(m4) * bf_lo(u4); ay += bf_hi(m4) * bf_hi(u4);
        ax += bf_hi(m5) * bf_lo(u5); ay += bf_hi(m5) * bf_hi(u5);
        ax += bf_hi(m6) * bf_lo(u6); ay += bf_hi(m6) * bf_hi(u6);
        ax += bf_hi(m7) * bf_lo(u7); ay += bf_hi(m7) * bf_hi(u7);
    }
    for (; j < t; ++j) {
        unsigned int m = meta[j];
        const float w = bf_hi(m);
        unsigned int u = hin[(size_t)(m & 0xffffu) * 64 + lane];
        ax += w * bf_lo(u); ay += w * bf_hi(u);
    }

    if (FINAL) {
        float2 bv = reinterpret_cast<const float2*>(bias)[lane];
        float2 o; o.x = d * ax + bv.x; o.y = d * ay + bv.y;
        reinterpret_cast<float2*>(hout)[(size_t)node * 64 + lane] = o;
    } else {
        const float d2 = d * d;
        unsigned int p = (unsigned int)f2bf(d2 * ax) |
                         ((unsigned int)f2bf(d2 * ay) << 16);
        reinterpret_cast<unsigned int*>(hout)[(size_t)node * 64 + lane] = p;
    }
}

extern "C" void kernel_launch(void* const* d_in, const int* in_sizes, int n_in,
                              void* d_out, int out_size, void* d_ws, size_t ws_size,
                              hipStream_t stream)
{
    const float* x  = (const float*)d_in[0];
    const int*   ei = (const int*)d_in[1];     // int32 (harness converts)
    const float* ew = (const float*)d_in[2];
    const float* W  = (const float*)d_in[3];
    const float* b  = (const float*)d_in[4];

    const int E  = in_sizes[2];
    const int H  = in_sizes[4];        // 128
    const int T  = in_sizes[3] / H;    // 256
    const int N  = in_sizes[0] / T;    // 50000  (< 65536: 16-bit ids valid)
    const int WT = in_sizes[3];        // 32768
    const int NB = (N + BK - 1) / BK;  // 196 buckets

    const int* rows = ei;              // sources
    const int* cols = ei + E;          // targets (aggregation index)

    // ---- workspace ----
    char* wsb = (char*)d_ws;
    unsigned int*   z    = (unsigned int*)wsb;   wsb += (size_t)N * (H / 2) * 4;  // 12.8 MB
    unsigned int*   z1   = (unsigned int*)wsb;   wsb += (size_t)N * (H / 2) * 4;  // 12.8 MB
    unsigned int*   meta = (unsigned int*)wsb;   wsb += (size_t)NB * CAP * 4;     // 6.4 MB
    unsigned short* Wbf  = (unsigned short*)wsb; wsb += (size_t)WT * 2;           // 64 KB
    float*          dis  = (float*)wsb;          wsb += (size_t)N * 4;
    int*            sta  = (int*)wsb;            wsb += (size_t)N * 4;
    int*            end_ = (int*)wsb;            wsb += (size_t)N * 4;
    int*            tails= (int*)wsb;            wsb += (size_t)NB * 4;
    // bucket staging aliases z1 (dead until hop1 output): bwr 6.4MB + bcl 1.6MB
    unsigned int*   bwr  = z1;                                  // NB*CAP*4
    unsigned char*  bcl  = (unsigned char*)(z1 + (size_t)NB * CAP);

    float* out = (float*)d_out;

    // CSR build: bucket two-pass
    hipMemsetAsync(tails, 0, (size_t)NB * 4, stream);
    {
        const int nblkA = (E + CHUNK - 1) / CHUNK;   // 196 (covers WT too)
        k_passA<<<nblkA, 256, 0, stream>>>(rows, cols, ew, E,
                                           bwr, bcl, tails, W, Wbf, WT);
        k_passB<<<NB, 256, 0, stream>>>(bwr, bcl, tails,
                                        meta, sta, end_, dis, N);
    }

    // transform: z = bf16(dis * (X W^T))
    {
        const int RB = 32;
        k_transform_mfma<<<(N + RB - 1) / RB, 256, 0, stream>>>(
            x, Wbf, dis, (unsigned short*)z, N);
    }

    // hops (hop1 overwrites z1 -> bucket staging dead by then)
    const int gH = (N + 3) / 4;
    k_hop<false><<<gH, 256, 0, stream>>>(sta, end_, meta, dis, z, nullptr, z1, N);
    k_hop<true ><<<gH, 256, 0, stream>>>(sta, end_, meta, dis, z1, b, out, N);
}

// Round 11
// 137.364 us; speedup vs baseline: 1.0328x; 1.0178x over previous
//
#include <hip/hip_runtime.h>

// ---------------------------------------------------------------------------
// SGConv (K=2): out = A^2 (X W^T) + b,  A = D^{-1/2}(Adj_clamped + I)D^{-1/2}
// N=50000, E=800000, T=256, H=128. edge_index arrives as int32.
//
// r11: transform staging with EXPLICIT 8-deep load MLP (v[8] regs loaded
// before any convert/ds_write) — r8/r9/r10 all serialized staging loads
// (VGPR 52-76 => compiler thrift), each thread had 1 outstanding HBM load.
// W frags in VGPRs (r10), x->LDS, pure ds_read+MFMA k-loop.
// CSR build: two-pass bucket sort (r8). Hops: unroll-8 gather (r7).
// ---------------------------------------------------------------------------

typedef __attribute__((ext_vector_type(8))) short short8_t;   // 8 bf16
typedef __attribute__((ext_vector_type(4))) float f32x4_t;    // MFMA acc

constexpr int BK    = 256;   // nodes per bucket
constexpr int CAP   = 8192;  // records per bucket (mean 4096 + 64 sigma)
constexpr int CHUNK = 4096;  // edges per passA block

__device__ inline unsigned short f2bf(float f) {               // RNE f32->bf16
    unsigned int u = __float_as_uint(f);
    return (unsigned short)((u + 0x7fffu + ((u >> 16) & 1u)) >> 16);
}
__device__ inline float bf_lo(unsigned int u) { return __uint_as_float(u << 16); }
__device__ inline float bf_hi(unsigned int u) { return __uint_as_float(u & 0xffff0000u); }

// ---- passA: bucket-bin edges; coalesced appends to bucket storage ----
__global__ __launch_bounds__(256) void k_passA(
    const int* __restrict__ rows, const int* __restrict__ cols,
    const float* __restrict__ ew, int E,
    unsigned int* __restrict__ bwr,   // [NB*CAP]  w<<16|row
    unsigned char* __restrict__ bcl,  // [NB*CAP]  col low byte
    int* __restrict__ tails,          // [NB]
    const float* __restrict__ W, unsigned short* __restrict__ Wbf, int WT)
{
    const int tid = threadIdx.x;
    const int gid = blockIdx.x * 256 + tid;
    if (gid < WT) Wbf[gid] = f2bf(W[gid]);       // fold W->bf16 conversion

    __shared__ unsigned short lcol[CHUNK], lrow[CHUNK], lw[CHUNK];
    __shared__ unsigned short sidx[CHUNK];
    __shared__ int hist[256], lofs[256], fill[256], gbase[256];

    const int e0  = blockIdx.x * CHUNK;
    const int cnt = min(CHUNK, E - e0);
    if (cnt <= 0) return;

    hist[tid] = 0; fill[tid] = 0;
    __syncthreads();

    for (int i = tid; i < cnt; i += 256) {
        const int c = cols[e0 + i];
        const int r = rows[e0 + i];
        float w = ew[e0 + i];
        w = (w > 0.0f) ? w : 1e-7f;              // elu(w)<=0 <=> w<=0
        lcol[i] = (unsigned short)c;
        lrow[i] = (unsigned short)r;
        lw[i]   = f2bf(w);
        atomicAdd(&hist[c >> 8], 1);
    }
    __syncthreads();

    // exclusive scan of hist -> lofs
    {
        const int v = hist[tid];
        lofs[tid] = v;
        __syncthreads();
        for (int off = 1; off < 256; off <<= 1) {
            int t = (tid >= off) ? lofs[tid - off] : 0;
            __syncthreads();
            lofs[tid] += t;
            __syncthreads();
        }
        const int excl = lofs[tid] - v;
        __syncthreads();
        lofs[tid] = excl;
        __syncthreads();
    }

    // rank within block -> sorted index
    for (int i = tid; i < cnt; i += 256) {
        const int b = lcol[i] >> 8;
        const int pos = lofs[b] + atomicAdd(&fill[b], 1);
        sidx[pos] = (unsigned short)i;
    }
    __syncthreads();

    // reserve global space: one atomic per non-empty bucket
    {
        const int h = hist[tid];
        gbase[tid] = (h > 0) ? atomicAdd(&tails[tid], h) : 0;
    }
    __syncthreads();

    // write out in bucket-sorted order (runs of consecutive addresses)
    for (int i = tid; i < cnt; i += 256) {
        const int e = sidx[i];
        const int b = lcol[e] >> 8;
        const int slot = gbase[b] + (i - lofs[b]);
        if (slot < CAP) {                         // overflow guard
            const int addr = b * CAP + slot;
            bwr[addr] = ((unsigned int)lw[e] << 16) | lrow[e];
            bcl[addr] = (unsigned char)(lcol[e] & 255);
        }
    }
}

// ---- passB: per-bucket LDS sort + dis/starts/ends; coalesced meta write ----
__global__ __launch_bounds__(256) void k_passB(
    const unsigned int* __restrict__ bwr, const unsigned char* __restrict__ bcl,
    const int* __restrict__ tails,
    unsigned int* __restrict__ meta, int* __restrict__ starts,
    int* __restrict__ ends, float* __restrict__ dis, int N)
{
    const int tid  = threadIdx.x;
    const int b    = blockIdx.x;
    const int base = b * CAP;
    const int cnt  = min(tails[b], CAP);

    __shared__ unsigned int  lwr[CAP];      // 32 KB
    __shared__ unsigned char lcl[CAP];      // 8 KB
    __shared__ unsigned int  srt[CAP];      // 32 KB
    __shared__ int hist[256], offs[256], fill[256];

    hist[tid] = 0; fill[tid] = 0;
    __syncthreads();

    for (int i = tid; i < cnt; i += 256) {
        lwr[i] = bwr[base + i];
        unsigned char c = bcl[base + i];
        lcl[i] = c;
        atomicAdd(&hist[c], 1);
    }
    __syncthreads();

    // exclusive scan of hist -> offs
    {
        const int v = hist[tid];
        offs[tid] = v;
        __syncthreads();
        for (int off = 1; off < 256; off <<= 1) {
            int t = (tid >= off) ? offs[tid - off] : 0;
            __syncthreads();
            offs[tid] += t;
            __syncthreads();
        }
        const int excl = offs[tid] - v;
        __syncthreads();
        offs[tid] = excl;
        __syncthreads();
    }

    // scatter to sorted order (LDS -> LDS)
    for (int i = tid; i < cnt; i += 256) {
        const int c = lcl[i];
        const int pos = offs[c] + atomicAdd(&fill[c], 1);
        srt[pos] = lwr[i];
    }
    __syncthreads();

    // coalesced meta write
    for (int i = tid; i < cnt; i += 256) meta[base + i] = srt[i];

    // per-node: dis = rsqrt(1 + sum w), starts/ends
    const int node = b * BK + tid;
    if (node < N) {
        const int s = offs[tid];
        const int t = s + hist[tid];
        float sum = 1.0f;                         // self-loop
        for (int j = s; j < t; ++j) sum += bf_hi(srt[j]);
        dis[node]    = rsqrtf(sum);
        starts[node] = base + s;
        ends[node]   = base + t;
    }
}

// ---- z[r][h] = bf16( dis[r] * dot(x[r], W[h]) ) via MFMA bf16 ----
// r11: explicit 8-deep staging MLP; W frags in VGPRs; x in LDS.
__global__ __launch_bounds__(256, 2) void k_transform_mfma(
    const float* __restrict__ x, const unsigned short* __restrict__ Wbf,
    const float* __restrict__ dis, unsigned short* __restrict__ z, int N)
{
    constexpr int RB  = 32;
    constexpr int LDK = 264;   // 256 + 8 pad shorts; row stride 528 B
    __shared__ unsigned short xs[RB][LDK];

    const int tid  = threadIdx.x;
    const int r0   = blockIdx.x * RB;
    const int wave = tid >> 6;
    const int lane = tid & 63;
    const int lr   = lane & 15;     // A-row / D-col within tile
    const int kg   = lane >> 4;     // k-group (8 consecutive k each)
    const int nb   = (wave & 1) * 4;    // n-tile base: cols nb*16 .. nb*16+63
    const int wr0  = (wave >> 1) * 16;  // row offset within block (0 or 16)

    // ---- stage x: issue ALL 8 independent float4 loads BEFORE any use ----
    const float4* x4 = reinterpret_cast<const float4*>(x);
    float4 v[8];
#pragma unroll
    for (int it = 0; it < 8; ++it) {
        const int i   = it * 256 + tid;          // RB*64 = 2048 = 8*256
        const int row = r0 + (i >> 6);
        v[it] = (row < N) ? x4[(size_t)row * 64 + (i & 63)]
                          : make_float4(0.f, 0.f, 0.f, 0.f);
    }

    // W preload: 32 independent 16B loads (L2-broadcast), overlaps x loads
    short8_t wf[4][8];
#pragma unroll
    for (int n = 0; n < 4; ++n)
#pragma unroll
        for (int k = 0; k < 8; ++k)
            wf[n][k] = *reinterpret_cast<const short8_t*>(
                Wbf + (size_t)((nb + n) * 16 + lr) * 256 + k * 32 + kg * 8);

    // convert + LDS write (consumes v[] as loads retire, oldest first)
#pragma unroll
    for (int it = 0; it < 8; ++it) {
        const int i = it * 256 + tid;
        unsigned short* p = &xs[i >> 6][(i & 63) * 4];
        p[0] = f2bf(v[it].x); p[1] = f2bf(v[it].y);
        p[2] = f2bf(v[it].z); p[3] = f2bf(v[it].w);
    }
    __syncthreads();

    f32x4_t acc[4];
#pragma unroll
    for (int n = 0; n < 4; ++n) acc[n] = (f32x4_t){0.f, 0.f, 0.f, 0.f};

#pragma unroll
    for (int k = 0; k < 8; ++k) {
        const short8_t af =
            *reinterpret_cast<const short8_t*>(&xs[wr0 + lr][k * 32 + kg * 8]);
#pragma unroll
        for (int n = 0; n < 4; ++n)
            acc[n] = __builtin_amdgcn_mfma_f32_16x16x32_bf16(af, wf[n][k],
                                                             acc[n], 0, 0, 0);
    }

    // D layout: col = lane&15, row = (lane>>4)*4 + reg   [m89/m91]
    float dsc[4];
#pragma unroll
    for (int r = 0; r < 4; ++r) {
        const int orow = r0 + wr0 + kg * 4 + r;
        dsc[r] = (orow < N) ? dis[orow] : 0.f;
    }
#pragma unroll
    for (int n = 0; n < 4; ++n) {
#pragma unroll
        for (int r = 0; r < 4; ++r) {
            const int orow = r0 + wr0 + kg * 4 + r;
            if (orow < N)
                z[(size_t)orow * 128 + (nb + n) * 16 + lr] =
                    f2bf(dsc[r] * acc[n][r]);
        }
    }
}

// ---- hop: one wave per dst node, unroll-8 independent gathers ----
// acc = z[c] + sum w*z[r];  FINAL: out=dis*acc+bias (f32); else bf16(dis^2*acc)
template <bool FINAL>
__global__ __launch_bounds__(256) void k_hop(
    const int* __restrict__ starts, const int* __restrict__ ends,
    const unsigned int* __restrict__ meta,
    const float* __restrict__ dis, const unsigned int* __restrict__ hin,
    const float* __restrict__ bias, void* __restrict__ hout, int N)
{
    const int wave = threadIdx.x >> 6;
    const int lane = threadIdx.x & 63;
    const int node = blockIdx.x * 4 + wave;
    if (node >= N) return;

    const int s = __builtin_amdgcn_readfirstlane(starts[node]);
    const int t = __builtin_amdgcn_readfirstlane(ends[node]);
    const float d = dis[node];

    unsigned int v = hin[(size_t)node * 64 + lane];
    float ax = bf_lo(v), ay = bf_hi(v);            // self term z[c]

    int j = s;
    for (; j + 8 <= t; j += 8) {
        unsigned int m0 = meta[j],     m1 = meta[j + 1];
        unsigned int m2 = meta[j + 2], m3 = meta[j + 3];
        unsigned int m4 = meta[j + 4], m5 = meta[j + 5];
        unsigned int m6 = meta[j + 6], m7 = meta[j + 7];
        unsigned int u0 = hin[(size_t)(m0 & 0xffffu) * 64 + lane];
        unsigned int u1 = hin[(size_t)(m1 & 0xffffu) * 64 + lane];
        unsigned int u2 = hin[(size_t)(m2 & 0xffffu) * 64 + lane];
        unsigned int u3 = hin[(size_t)(m3 & 0xffffu) * 64 + lane];
        unsigned int u4 = hin[(size_t)(m4 & 0xffffu) * 64 + lane];
        unsigned int u5 = hin[(size_t)(m5 & 0xffffu) * 64 + lane];
        unsigned int u6 = hin[(size_t)(m6 & 0xffffu) * 64 + lane];
        unsigned int u7 = hin[(size_t)(m7 & 0xffffu) * 64 + lane];
        ax += bf_hi(m0) * bf_lo(u0); ay += bf_hi(m0) * bf_hi(u0);
        ax += bf_hi(m1) * bf_lo(u1); ay += bf_hi(m1) * bf_hi(u1);
        ax += bf_hi(m2) * bf_lo(u2); ay += bf_hi(m2) * bf_hi(u2);
        ax += bf_hi(m3) * bf_lo(u3); ay += bf_hi(m3) * bf_hi(u3);
        ax += bf_hi(m4) * bf_lo(u4); ay += bf_hi(m4) * bf_hi(u4);
        ax += bf_hi(m5) * bf_lo(u5); ay += bf_hi(m5) * bf_hi(u5);
        ax += bf_hi(m6) * bf_lo(u6); ay += bf_hi(m6) * bf_hi(u6);
        ax += bf_hi(m7) * bf_lo(u7); ay += bf_hi(m7) * bf_hi(u7);
    }
    for (; j < t; ++j) {
        unsigned int m = meta[j];
        const float w = bf_hi(m);
        unsigned int u = hin[(size_t)(m & 0xffffu) * 64 + lane];
        ax += w * bf_lo(u); ay += w * bf_hi(u);
    }

    if (FINAL) {
        float2 bv = reinterpret_cast<const float2*>(bias)[lane];
        float2 o; o.x = d * ax + bv.x; o.y = d * ay + bv.y;
        reinterpret_cast<float2*>(hout)[(size_t)node * 64 + lane] = o;
    } else {
        const float d2 = d * d;
        unsigned int p = (unsigned int)f2bf(d2 * ax) |
                         ((unsigned int)f2bf(d2 * ay) << 16);
        reinterpret_cast<unsigned int*>(hout)[(size_t)node * 64 + lane] = p;
    }
}

extern "C" void kernel_launch(void* const* d_in, const int* in_sizes, int n_in,
                              void* d_out, int out_size, void* d_ws, size_t ws_size,
                              hipStream_t stream)
{
    const float* x  = (const float*)d_in[0];
    const int*   ei = (const int*)d_in[1];     // int32 (harness converts)
    const float* ew = (const float*)d_in[2];
    const float* W  = (const float*)d_in[3];
    const float* b  = (const float*)d_in[4];

    const int E  = in_sizes[2];
    const int H  = in_sizes[4];        // 128
    const int T  = in_sizes[3] / H;    // 256
    const int N  = in_sizes[0] / T;    // 50000  (< 65536: 16-bit ids valid)
    const int WT = in_sizes[3];        // 32768
    const int NB = (N + BK - 1) / BK;  // 196 buckets

    const int* rows = ei;              // sources
    const int* cols = ei + E;          // targets (aggregation index)

    // ---- workspace ----
    char* wsb = (char*)d_ws;
    unsigned int*   z    = (unsigned int*)wsb;   wsb += (size_t)N * (H / 2) * 4;  // 12.8 MB
    unsigned int*   z1   = (unsigned int*)wsb;   wsb += (size_t)N * (H / 2) * 4;  // 12.8 MB
    unsigned int*   meta = (unsigned int*)wsb;   wsb += (size_t)NB * CAP * 4;     // 6.4 MB
    unsigned short* Wbf  = (unsigned short*)wsb; wsb += (size_t)WT * 2;           // 64 KB
    float*          dis  = (float*)wsb;          wsb += (size_t)N * 4;
    int*            sta  = (int*)wsb;            wsb += (size_t)N * 4;
    int*            end_ = (int*)wsb;            wsb += (size_t)N * 4;
    int*            tails= (int*)wsb;            wsb += (size_t)NB * 4;
    // bucket staging aliases z1 (dead until hop1 output): bwr 6.4MB + bcl 1.6MB
    unsigned int*   bwr  = z1;                                  // NB*CAP*4
    unsigned char*  bcl  = (unsigned char*)(z1 + (size_t)NB * CAP);

    float* out = (float*)d_out;

    // CSR build: bucket two-pass
    hipMemsetAsync(tails, 0, (size_t)NB * 4, stream);
    {
        const int nblkA = (E + CHUNK - 1) / CHUNK;   // 196 (covers WT too)
        k_passA<<<nblkA, 256, 0, stream>>>(rows, cols, ew, E,
                                           bwr, bcl, tails, W, Wbf, WT);
        k_passB<<<NB, 256, 0, stream>>>(bwr, bcl, tails,
                                        meta, sta, end_, dis, N);
    }

    // transform: z = bf16(dis * (X W^T))
    {
        const int RB = 32;
        k_transform_mfma<<<(N + RB - 1) / RB, 256, 0, stream>>>(
            x, Wbf, dis, (unsigned short*)z, N);
    }

    // hops (hop1 overwrites z1 -> bucket staging dead by then)
    const int gH = (N + 3) / 4;
    k_hop<false><<<gH, 256, 0, stream>>>(sta, end_, meta, dis, z, nullptr, z1, N);
    k_hop<true ><<<gH, 256, 0, stream>>>(sta, end_, meta, dis, z1, b, out, N);
}